// Round 4
// baseline (340.417 us; speedup 1.0000x reference)
//
#include <hip/hip_runtime.h>

// Problem constants (fixed by setup_inputs)
#define BQ   4
#define CQ   2
#define EQ   256
#define LQ   16000
#define WQ   40
#define STEP 20
#define TQ   ((LQ - 1) * STEP + WQ)   // 320020
#define TLF  63                       // owned-frame pitch per block (64 computed, 1 overlap)
#define OWN  (TLF * STEP)             // 1260 owned output samples per block
#define NBX  254                      // 254 * 1260 = 320040 >= 320020
#define NH   8                        // e-octants (channels merged into each thread)
#define EH   (EQ / NH)                // 32 e's per thread
#define NG   (EH / 2)                 // 16 groups of 2 e's
#define NCP  4                        // LDS accumulation copies (one per octant pair)
#define SPAN (TLF * STEP + WQ + STEP) // 1320 floats per (copy, c)

// Pre-kernel: transpose basis [W][E] -> wsT [E][W] (fp32, rows contiguous)
// so the main loop can read each e-row with wave-uniform scalar loads.
__global__ void transpose_basis_kernel(const float* __restrict__ basis,
                                       float* __restrict__ wsT) {
    int i = blockIdx.x * 256 + threadIdx.x;
    if (i < EQ * WQ) {
        int e = i / WQ;
        int w = i - e * WQ;
        wsT[i] = basis[w * EQ + e];
    }
}

// One block: 512 threads = 8 e-octants (h) x 64 frames (ll); both channels per
// thread. The K loop is a fully-unrolled straight-line software pipeline:
// group t's 6 loads are issued 4 groups (~1280 issue-cycles of FMA) before
// their use, into plain registers (constant-indexed arrays -> stay in VGPRs,
// compiler emits counted vmcnt(N) at first use, never a forced drain).
// Basis offsets are all literal constants -> proven-uniform s_load path.
// Overlap-add into 4 LDS copies, 4 serialized parity phases -> no atomics.
__global__ __launch_bounds__(512, 4) void decoder_kernel(
    const float* __restrict__ mix,    // [B,E,L]
    const float* __restrict__ mask,   // [B,C,E,L]
    const float* __restrict__ wsT,    // [E,W] transposed basis
    float* __restrict__ out)          // [B,C,T]
{
    __shared__ float outS[NCP][CQ][SPAN];   // ~42 KB

    const int tid = threadIdx.x;
    const int ll  = tid & 63;                                  // frame lane
    const int h   = __builtin_amdgcn_readfirstlane(tid >> 6);  // e-octant, forced uniform
    const int bx  = blockIdx.x;
    const int b   = blockIdx.y;
    const int f   = TLF * bx - 1 + ll;   // may be out of [0,LQ)

    // Clamp + validity multiplier: keeps the K-loop branch-free so the
    // wave-uniform basis loads can be scalarized (no divergent CF).
    const int   fc    = min(max(f, 0), LQ - 1);
    const float valid = (f >= 0 && f < LQ) ? 1.0f : 0.0f;

    float acc0[WQ], acc1[WQ];
#pragma unroll
    for (int w = 0; w < WQ; ++w) { acc0[w] = 0.0f; acc1[w] = 0.0f; }

    const float* mp  = mix  + ((size_t)b * EQ + h * EH) * LQ + fc;
    const float* kp0 = mask + (((size_t)(b * CQ)) * EQ + h * EH) * LQ + fc;
    const float* kp1 = kp0 + (size_t)EQ * LQ;      // channel 1 mask
    const float* bp  = wsT + (size_t)h * EH * WQ;  // wave-uniform

    // In-flight register file for the pipeline (constant indices only).
    float md0[NG], md1[NG], kd00[NG], kd01[NG], kd10[NG], kd11[NG];

#define ISSUE(t) do { \
    md0[t]  = mp [(size_t)(2*(t)    ) * LQ]; \
    md1[t]  = mp [(size_t)(2*(t) + 1) * LQ]; \
    kd00[t] = kp0[(size_t)(2*(t)    ) * LQ]; \
    kd01[t] = kp0[(size_t)(2*(t) + 1) * LQ]; \
    kd10[t] = kp1[(size_t)(2*(t)    ) * LQ]; \
    kd11[t] = kp1[(size_t)(2*(t) + 1) * LQ]; \
    __builtin_amdgcn_sched_barrier(0); \
} while (0)

#define FMAG(t) do { \
    const float k00 = kd00[t] * valid, k01 = kd01[t] * valid; \
    const float k10 = kd10[t] * valid, k11 = kd11[t] * valid; \
    { const float s0 = md0[t] * k00, s1 = md0[t] * k10; \
      const float* bb = bp + (2*(t)) * WQ; \
      _Pragma("unroll") \
      for (int w = 0; w < WQ; ++w) { \
          acc0[w] = fmaf(s0, bb[w], acc0[w]); \
          acc1[w] = fmaf(s1, bb[w], acc1[w]); \
      } } \
    { const float s0 = md1[t] * k01, s1 = md1[t] * k11; \
      const float* bb = bp + (2*(t) + 1) * WQ; \
      _Pragma("unroll") \
      for (int w = 0; w < WQ; ++w) { \
          acc0[w] = fmaf(s0, bb[w], acc0[w]); \
          acc1[w] = fmaf(s1, bb[w], acc1[w]); \
      } } \
} while (0)

    // Prologue: 4 groups (24 loads) in flight before the first FMA.
    ISSUE(0); ISSUE(1); ISSUE(2); ISSUE(3);
    // Steady state: issue group t+4 ahead of computing group t.
    ISSUE(4);  FMAG(0);
    ISSUE(5);  FMAG(1);
    ISSUE(6);  FMAG(2);
    ISSUE(7);  FMAG(3);
    ISSUE(8);  FMAG(4);
    ISSUE(9);  FMAG(5);
    ISSUE(10); FMAG(6);
    ISSUE(11); FMAG(7);
    ISSUE(12); FMAG(8);
    ISSUE(13); FMAG(9);
    ISSUE(14); FMAG(10);
    ISSUE(15); FMAG(11);
    // Epilogue: drain the last 4 groups.
    FMAG(12); FMAG(13); FMAG(14); FMAG(15);

#undef ISSUE
#undef FMAG

    // Overlap-add into LDS copy cp = h>>1. 4 serialized parity phases
    // (h-parity x ll-parity); even-ll ranges [20*ll,20*ll+40) tile [0,1280)
    // exactly, so phase 0 is a plain store (no pre-zero needed; indices
    // [1280,1300) are written by odd-ll adds but never read back).
    const int base = ll * STEP;
    const int cp   = h >> 1;
    const int hp   = h & 1;
    if (hp == 0 && (ll & 1) == 0) {
#pragma unroll
        for (int w = 0; w < WQ; ++w) {
            outS[cp][0][base + w] = acc0[w];
            outS[cp][1][base + w] = acc1[w];
        }
    }
    __syncthreads();
    if (hp == 0 && (ll & 1) == 1) {
#pragma unroll
        for (int w = 0; w < WQ; ++w) {
            outS[cp][0][base + w] += acc0[w];
            outS[cp][1][base + w] += acc1[w];
        }
    }
    __syncthreads();
    if (hp == 1 && (ll & 1) == 0) {
#pragma unroll
        for (int w = 0; w < WQ; ++w) {
            outS[cp][0][base + w] += acc0[w];
            outS[cp][1][base + w] += acc1[w];
        }
    }
    __syncthreads();
    if (hp == 1 && (ll & 1) == 1) {
#pragma unroll
        for (int w = 0; w < WQ; ++w) {
            outS[cp][0][base + w] += acc0[w];
            outS[cp][1][base + w] += acc1[w];
        }
    }
    __syncthreads();

    // Store owned span: t = 1260*bx + i  <->  outS[*][c][20 + i], i in [0,1260)
    for (int cc = 0; cc < CQ; ++cc) {
        const size_t ob = ((size_t)b * CQ + cc) * TQ + (size_t)OWN * bx;
        for (int i = tid; i < OWN; i += 512) {
            const long t = (long)OWN * bx + i;
            if (t < (long)TQ) {
                out[ob + i] = outS[0][cc][STEP + i] + outS[1][cc][STEP + i]
                            + outS[2][cc][STEP + i] + outS[3][cc][STEP + i];
            }
        }
    }
}

extern "C" void kernel_launch(void* const* d_in, const int* in_sizes, int n_in,
                              void* d_out, int out_size, void* d_ws, size_t ws_size,
                              hipStream_t stream) {
    const float* mix   = (const float*)d_in[0];
    const float* mask  = (const float*)d_in[1];
    const float* basis = (const float*)d_in[2];
    float* out = (float*)d_out;
    float* wsT = (float*)d_ws;   // needs EQ*WQ*4 = 40960 bytes

    transpose_basis_kernel<<<dim3((EQ * WQ + 255) / 256), 256, 0, stream>>>(basis, wsT);

    dim3 grid(NBX, BQ);
    decoder_kernel<<<grid, 512, 0, stream>>>(mix, mask, wsT, out);
}